// Round 14
// baseline (220.050 us; speedup 1.0000x reference)
//
#include <hip/hip_runtime.h>
#include <stdint.h>

// ---------------------------------------------------------------------------
// Fused wavelet window-attention; affine qk addressing (no swizzle), exp2.
//   Block = 512 thr: one (unit, quarter) = 4 orig rows x 64 orig cols.
//   smem 80KB = bands[4][c64][px64] f16 XOR-swz (32KB) + qk 48KB (linear).
//   qk granule(G,np,W) 16B at u16 idx G*256+np*128+W*8: channels
//   {4G+2np,+1} x q(4 spatial). Attention reads are 16-lane broadcasts ->
//   conflict-free with LINEAR layout; affine addresses let the compiler use
//   ds_read offset: immediates (R13 analysis: XOR swizzle bought nothing and
//   cost ~700 VALU/thread of address math).
//   exp(x) computed as exp2((s*log2e)*qk) -- log2e folded into Q scale.
//   y parked as packed half2 in dead band slabs (no spill, R11-verified).
// ---------------------------------------------------------------------------

typedef _Float16 halfT;
typedef __attribute__((ext_vector_type(2))) _Float16 half2T;
typedef __attribute__((ext_vector_type(8))) _Float16 half8;
typedef __attribute__((ext_vector_type(4))) float f32x4;

union H8 { half8 v; half2T h2[4]; uint16_t s[8]; };
union H2U { half2T h; uint32_t u; };

static __device__ __forceinline__ uint16_t f2h(float f){
  union { halfT h; uint16_t u; } x; x.h = (halfT)f; return x.u;
}
static __device__ __forceinline__ float h2f(uint16_t u){
  union { uint16_t u; halfT h; } x; x.u = u; return (float)x.h;
}
static __device__ __forceinline__ float dot4(half2T a0, half2T a1,
                                             half2T b0, half2T b1){
#if __has_builtin(__builtin_amdgcn_fdot2)
  return __builtin_amdgcn_fdot2(a1, b1, __builtin_amdgcn_fdot2(a0, b0, 0.f, false), false);
#else
  half2T p = a0*b0 + a1*b1;
  return (float)p.x + (float)p.y;
#endif
}
static __device__ __forceinline__ half2T pk2(float e){
#if __has_builtin(__builtin_amdgcn_cvt_pkrtz)
  union { __fp16 __attribute__((ext_vector_type(2))) p; half2T h; } c;
  c.p = __builtin_amdgcn_cvt_pkrtz(e, e);
  return c.h;
#else
  half2T r; r.x = (halfT)e; r.y = (halfT)e; return r;
#endif
}

__global__ void k_wt(const float* __restrict__ wlh, const float* __restrict__ wm,
                     halfT* __restrict__ wH){
  int i = blockIdx.x * 256 + threadIdx.x;
  if (i < 12288)      wH[i] = (halfT)wlh[i];
  else if (i < 61440) wH[i] = (halfT)wm[i - 12288];
}

#define OT_CS 276
#define OT_RS 68
// exp2-folded scales: scale * log2(e)
#define SC_LH 0.36067376022224085f   // 0.25 * 1.4426950408889634
#define SC_M  0.25506120808935443f   // 0.17677669529663687 * 1.4426950408889634

// low/high conv: K=64, T=192; 12 M-tiles split by ms; linear qk writes
static __device__ __forceinline__ void conv64(const halfT* __restrict__ w,
    const uint16_t* __restrict__ bands, uint16_t* __restrict__ qk,
    int band, int mrow, int g, int ms, int pxb, int qoff){
  half8 bfr[2];
  #pragma unroll
  for (int ks = 0; ks < 2; ++ks){
    H8 t; int cb = ks*32 + g*8;
    #pragma unroll
    for (int k = 0; k < 8; ++k)
      t.s[k] = bands[band*4096 + (cb + k)*64 + (pxb ^ (g << 4))];
    bfr[ks] = t.v;
  }
  #pragma unroll
  for (int mi = 0; mi < 6; ++mi){
    int mt = ms*6 + mi;
    f32x4 acc = {0.f,0.f,0.f,0.f};
    #pragma unroll
    for (int ks = 0; ks < 2; ++ks){
      half8 a = *(const half8*)&w[(mt*16 + mrow)*64 + ks*32 + g*8];
      acc = __builtin_amdgcn_mfma_f32_16x16x32_f16(a, bfr[ks], acc, 0, 0, 0);
    }
    uint16_t* wp = qk + qoff + mt*1024;
    wp[0]   = f2h(acc[0]);           // r0: np0, +0
    wp[4]   = f2h(acc[1]);           // r1: np0, +4
    wp[128] = f2h(acc[2]);           // r2: np1, +0
    wp[132] = f2h(acc[3]);           // r3: np1, +4
  }
}

// low/high attention, packed-f16 PV -> park 4 u32 into yslab
static __device__ __forceinline__ void attn16p(const uint16_t* __restrict__ qk,
    int m, int np, int W, uint32_t* __restrict__ yslab, int tid){
  const halfT sh = (halfT)SC_LH;
  const half8 s8 = {sh,sh,sh,sh,sh,sh,sh,sh};
  const uint16_t* qb_ = qk + (m >> 1)*256 + np*128 + W*8;
  const uint16_t* kb_ = qk + 4096  + np*128 + W*8;
  const uint16_t* vb_ = qk + 8192  + np*128 + W*8;
  H8 qg; qg.v = (*(const half8*)qb_) * s8;
  float sum0 = 0.f, sum1 = 0.f;
  half2T A0 = {(halfT)0,(halfT)0}, A1 = A0, B0 = A0, B1 = A0;
  #pragma unroll
  for (int d = 0; d < 16; ++d){
    H8 kg, vg;
    kg.v = *(const half8*)&kb_[d*256];
    vg.v = *(const half8*)&vb_[d*256];
    float a0 = dot4(qg.h2[0], qg.h2[1], kg.h2[0], kg.h2[1]);
    float a1 = dot4(qg.h2[2], qg.h2[3], kg.h2[2], kg.h2[3]);
    float e0 = exp2f(a0), e1 = exp2f(a1);
    sum0 += e0; sum1 += e1;
    half2T p0 = pk2(e0), p1 = pk2(e1);
    A0 += p0*vg.h2[0]; A1 += p0*vg.h2[1];
    B0 += p1*vg.h2[2]; B1 += p1*vg.h2[3];
  }
  halfT i0 = (halfT)__builtin_amdgcn_rcpf(sum0);
  halfT i1 = (halfT)__builtin_amdgcn_rcpf(sum1);
  half2T v0 = {i0,i0}, v1 = {i1,i1};
  H2U u0, u1, u2, u3;
  u0.h = A0*v0; u1.h = A1*v0; u2.h = B0*v1; u3.h = B1*v1;
  yslab[0*512 + tid] = u0.u;
  yslab[1*512 + tid] = u1.u;
  yslab[2*512 + tid] = u2.u;
  yslab[3*512 + tid] = u3.u;
}

#define IDWT(CH, Y0, Y1, Y2, Y3) { \
  float* otc = ot + (CH)*OT_CS + gw*4; \
  _Pragma("unroll") \
  for (int rp = 0; rp < 2; ++rp){ \
    float4 top, bot; \
    _Pragma("unroll") \
    for (int cp = 0; cp < 2; ++cp){ \
      int s2 = rp*2 + cp; \
      float ll = Y0[s2], lh = Y1[s2], hl = Y2[s2], hh = Y3[s2]; \
      float va = 0.5f*(ll - lh - hl + hh); \
      float vb = 0.5f*(ll - lh + hl - hh); \
      float vc = 0.5f*(ll + lh - hl - hh); \
      float vd = 0.5f*(ll + lh + hl + hh); \
      if (cp == 0){ top.x = va; top.y = vb; bot.x = vc; bot.y = vd; } \
      else        { top.z = va; top.w = vb; bot.z = vc; bot.w = vd; } \
    } \
    *(float4*)&otc[(2*rp)*OT_RS]   = top; \
    *(float4*)&otc[(2*rp+1)*OT_RS] = bot; \
  } }

__global__ __launch_bounds__(512, 4) void k_fused(const float* __restrict__ x,
    const halfT* __restrict__ wH, float* __restrict__ out){
  __shared__ __align__(16) uint8_t smem[81920];
  uint16_t* bands = (uint16_t*)smem;                 // 32768 B
  uint16_t* qk    = (uint16_t*)(smem + 32768);       // 49152 B
  uint32_t* ybuf  = (uint32_t*)smem;                 // y slabs (dead bands)
  float*    ot    = (float*)smem;                    // reused at end

  const int tid = threadIdx.x;
  const int wv = tid >> 6, lane = tid & 63;
  const int unit = blockIdx.x >> 2, q4 = blockIdx.x & 3;
  const int b = unit >> 6, hw = unit & 63;
  const int col0 = q4 * 64;
  const float* xb = x + (size_t)b * 64 * 65536;
  const halfT* wM = wH + 12288;

  // ---------------- phase A: load x + Haar DWT -> bands -------------------
  #pragma unroll
  for (int it = 0; it < 4; ++it){
    int idx = it*512 + tid;
    int j = idx & 15, rp = (idx >> 4) & 1, c = idx >> 5;
    const float* src = xb + (size_t)c*65536 + (size_t)(4*hw + 2*rp)*256 + col0 + 4*j;
    float4 r0 = *(const float4*)src;
    float4 r1 = *(const float4*)(src + 256);
    float v0[4], v1[4];
    v0[0] = 0.5f*( r0.x + r0.y + r1.x + r1.y);
    v0[1] = 0.5f*(-r0.x - r0.y + r1.x + r1.y);
    v0[2] = 0.5f*(-r0.x + r0.y - r1.x + r1.y);
    v0[3] = 0.5f*( r0.x - r0.y - r1.x + r1.y);
    v1[0] = 0.5f*( r0.z + r0.w + r1.z + r1.w);
    v1[1] = 0.5f*(-r0.z - r0.w + r1.z + r1.w);
    v1[2] = 0.5f*(-r0.z + r0.w - r1.z + r1.w);
    v1[3] = 0.5f*( r0.z - r0.w - r1.z + r1.w);
    int base = c*64 + ((rp*32 + 2*j) ^ (((c >> 3) & 3) << 4));
    #pragma unroll
    for (int bb = 0; bb < 4; ++bb)
      *(uint32_t*)&bands[bb*4096 + base] =
          (uint32_t)f2h(v0[bb]) | ((uint32_t)f2h(v1[bb]) << 16);
  }
  __syncthreads();

  const int mrow = lane & 15, g = lane >> 4;
  const int m = lane & 31;
  const int W = wv*2 + (lane >> 5);   // window 0..15, fixed per thread
  const int A = 2*m;                  // output ch pair base
  const int np = m & 1;
  const int pxb = (wv & 3)*16 + mrow; // conv N-column
  const int wl = (pxb & 31) >> 1, qq = (pxb >> 5)*2 + (pxb & 1);
  const int ms = wv >> 2;
  const int qoff = g*256 + wl*8 + qq; // conv write base (linear layout)

  // ---- LOW ----
  conv64(wH, bands, qk, 0, mrow, g, ms, pxb, qoff);
  __syncthreads();
  attn16p(qk, m, np, W, ybuf + 0*2048, tid);   // y0 -> dead bands[0]
  __syncthreads();

  // ---- MID conv: K=128 (bands 1,2), T=384, 24 M-tiles split by ms ----
  {
    half8 bfr[4];
    #pragma unroll
    for (int ks = 0; ks < 4; ++ks){
      H8 t; int band = 1 + (ks >> 1); int cb = (ks & 1)*32 + g*8;
      #pragma unroll
      for (int k = 0; k < 8; ++k)
        t.s[k] = bands[band*4096 + (cb + k)*64 + (pxb ^ (g << 4))];
      bfr[ks] = t.v;
    }
    #pragma unroll
    for (int mi = 0; mi < 12; ++mi){
      int mt = ms*12 + mi;
      f32x4 acc = {0.f,0.f,0.f,0.f};
      #pragma unroll
      for (int ks = 0; ks < 4; ++ks){
        half8 a = *(const half8*)&wM[(mt*16 + mrow)*128 + ks*32 + g*8];
        acc = __builtin_amdgcn_mfma_f32_16x16x32_f16(a, bfr[ks], acc, 0, 0, 0);
      }
      uint16_t* wp = qk + qoff + mt*1024;
      wp[0]   = f2h(acc[0]);
      wp[4]   = f2h(acc[1]);
      wp[128] = f2h(acc[2]);
      wp[132] = f2h(acc[3]);
    }
  }
  __syncthreads();

  // ---- MID attention: single pass, packed-f16 PV; Q G0-31, K 32-63, V 64-95
  {
    const halfT shm = (halfT)SC_M;
    const half8 s8m = {shm,shm,shm,shm,shm,shm,shm,shm};
    const uint16_t* qa_ = qk + (m >> 1)*256 + np*128 + W*8;
    const uint16_t* kb_ = qk + 8192  + np*128 + W*8;   // G=32
    const uint16_t* vb_ = qk + 16384 + np*128 + W*8;   // G=64
    H8 qa, qb;
    qa.v = (*(const half8*)qa_) * s8m;                 // lh rows
    qb.v = (*(const half8*)&qa_[4096]) * s8m;          // hl rows (G+16)
    float sm0 = 0.f, sm1 = 0.f, sm2 = 0.f, sm3 = 0.f;
    half2T P0a = {(halfT)0,(halfT)0}, P0b = P0a, P1a = P0a, P1b = P0a;
    half2T P2a = P0a, P2b = P0a, P3a = P0a, P3b = P0a;
    #pragma unroll
    for (int dl = 0; dl < 32; ++dl){
      H8 kg, vg;
      kg.v = *(const half8*)&kb_[dl*256];
      vg.v = *(const half8*)&vb_[dl*256];
      float a0 = dot4(qa.h2[0], qa.h2[1], kg.h2[0], kg.h2[1]);
      float a1 = dot4(qa.h2[2], qa.h2[3], kg.h2[2], kg.h2[3]);
      float a2 = dot4(qb.h2[0], qb.h2[1], kg.h2[0], kg.h2[1]);
      float a3 = dot4(qb.h2[2], qb.h2[3], kg.h2[2], kg.h2[3]);
      float e0 = exp2f(a0), e1 = exp2f(a1);
      float e2 = exp2f(a2), e3 = exp2f(a3);
      sm0 += e0; sm1 += e1; sm2 += e2; sm3 += e3;
      half2T p0 = pk2(e0), p1 = pk2(e1), p2 = pk2(e2), p3 = pk2(e3);
      P0a += p0*vg.h2[0]; P0b += p0*vg.h2[1];
      P1a += p1*vg.h2[2]; P1b += p1*vg.h2[3];
      P2a += p2*vg.h2[0]; P2b += p2*vg.h2[1];
      P3a += p3*vg.h2[2]; P3b += p3*vg.h2[3];
    }
    halfT i0 = (halfT)__builtin_amdgcn_rcpf(sm0);
    halfT i1 = (halfT)__builtin_amdgcn_rcpf(sm1);
    halfT i2 = (halfT)__builtin_amdgcn_rcpf(sm2);
    halfT i3 = (halfT)__builtin_amdgcn_rcpf(sm3);
    half2T v0 = {i0,i0}, v1 = {i1,i1}, v2 = {i2,i2}, v3 = {i3,i3};
    uint32_t* y1s = ybuf + 1*2048;          // dead bands[1]
    uint32_t* y2s = ybuf + 2*2048;          // dead bands[2]
    H2U a0u, a1u, b0u, b1u, c0u, c1u, d0u, d1u;
    a0u.h = P0a*v0; a1u.h = P0b*v0; b0u.h = P1a*v1; b1u.h = P1b*v1;
    c0u.h = P2a*v2; c1u.h = P2b*v2; d0u.h = P3a*v3; d1u.h = P3b*v3;
    y1s[0*512 + tid] = a0u.u;
    y1s[1*512 + tid] = a1u.u;
    y1s[2*512 + tid] = b0u.u;
    y1s[3*512 + tid] = b1u.u;
    y2s[0*512 + tid] = c0u.u;
    y2s[1*512 + tid] = c1u.u;
    y2s[2*512 + tid] = d0u.u;
    y2s[3*512 + tid] = d1u.u;
  }
  __syncthreads();

  // ---- HIGH ----
  conv64(wH, bands, qk, 3, mrow, g, ms, pxb, qoff);
  __syncthreads();
  attn16p(qk, m, np, W, ybuf + 3*2048, tid);   // y3 -> dead bands[3]

  // ---- read own y0-y3 (written by this thread; no barrier needed) ----
  float ya[4][2][4];
  #pragma unroll
  for (int p = 0; p < 4; ++p){
    #pragma unroll
    for (int w = 0; w < 4; ++w){
      uint32_t u = ybuf[p*2048 + w*512 + tid];
      ya[p][w >> 1][(w & 1)*2 + 0] = h2f((uint16_t)(u & 0xffffu));
      ya[p][w >> 1][(w & 1)*2 + 1] = h2f((uint16_t)(u >> 16));
    }
  }
  __syncthreads();   // everyone done reading smem; smem becomes ot

  // ---- iDWT in registers -> ot staging ----
  {
    const int gw = W ^ (m & 15);
    IDWT(A,     ya[0][0], ya[1][0], ya[2][0], ya[3][0]);
    IDWT(A + 1, ya[0][1], ya[1][1], ya[2][1], ya[3][1]);
  }
  __syncthreads();

  // ---- coalesced store (full-line writes) ----
  #pragma unroll
  for (int it = 0; it < 2; ++it){
    int s = it*512 + tid;
    int ch = s >> 4, row = (s >> 2) & 3, seg = s & 3;
    int sw = (ch >> 1) & 15;
    const float* rowp = &ot[ch*OT_CS + row*OT_RS];
    float4 v0 = *(const float4*)&rowp[((seg*4+0) ^ sw)*4];
    float4 v1 = *(const float4*)&rowp[((seg*4+1) ^ sw)*4];
    float4 v2 = *(const float4*)&rowp[((seg*4+2) ^ sw)*4];
    float4 v3 = *(const float4*)&rowp[((seg*4+3) ^ sw)*4];
    float* dst = out + (((size_t)b*64 + ch)*256 + (size_t)(4*hw + row))*256 + col0 + seg*16;
    ((float4*)dst)[0] = v0; ((float4*)dst)[1] = v1;
    ((float4*)dst)[2] = v2; ((float4*)dst)[3] = v3;
  }
}

// ---------------------------------------------------------------------------
extern "C" void kernel_launch(void* const* d_in, const int* in_sizes, int n_in,
                              void* d_out, int out_size, void* d_ws, size_t ws_size,
                              hipStream_t stream){
  const float* x   = (const float*)d_in[0];
  const float* wlh = (const float*)d_in[1];
  const float* wm  = (const float*)d_in[2];
  float* out = (float*)d_out;
  halfT* wH = (halfT*)d_ws;                // 61440 f16 = 122880 B

  hipLaunchKernelGGL(k_wt,    dim3(240),  dim3(256), 0, stream, wlh, wm, wH);
  hipLaunchKernelGGL(k_fused, dim3(2048), dim3(512), 0, stream, x, wH, out);
}

// Round 16
// 209.387 us; speedup vs baseline: 1.0509x; 1.0509x over previous
//
#include <hip/hip_runtime.h>
#include <stdint.h>

// ---------------------------------------------------------------------------
// Fused wavelet window-attention; low+high co-resident in qk, 6 barriers.
//   Block = 512 thr: one (unit, quarter) = 4 orig rows x 64 orig cols.
//   smem 80KB = bands[4][c64][px64] f16 XOR-swz (32KB) + qk 48KB (linear).
//   qk capacity = 24576 u16. low [0:12288), high [12288:24576) co-resident
//   (R15 ERRATA: all-three-resident needs 98KB -- doesn't fit; mid alone
//   needs the full 48KB). granule(G,np,W) 16B at region + G*256+np*128+W*8.
//   Phases: A:DWT |b1| convL+convH |b2| attnL+attnH (park y0,y3 in dead
//   bands[0],[3]) |b3| convM (full qk) |b4| attnM (park y1,y2) + own-readback
//   |b5| iDWT->ot |b6| store.
//   exp2 with log2e folded into Q scale; packed-f16 PV; y parked in dead
//   band slabs (no spill) -- all R11-R14-verified pieces.
// ---------------------------------------------------------------------------

typedef _Float16 halfT;
typedef __attribute__((ext_vector_type(2))) _Float16 half2T;
typedef __attribute__((ext_vector_type(8))) _Float16 half8;
typedef __attribute__((ext_vector_type(4))) float f32x4;

union H8 { half8 v; half2T h2[4]; uint16_t s[8]; };
union H2U { half2T h; uint32_t u; };

static __device__ __forceinline__ uint16_t f2h(float f){
  union { halfT h; uint16_t u; } x; x.h = (halfT)f; return x.u;
}
static __device__ __forceinline__ float h2f(uint16_t u){
  union { uint16_t u; halfT h; } x; x.u = u; return (float)x.h;
}
static __device__ __forceinline__ float dot4(half2T a0, half2T a1,
                                             half2T b0, half2T b1){
#if __has_builtin(__builtin_amdgcn_fdot2)
  return __builtin_amdgcn_fdot2(a1, b1, __builtin_amdgcn_fdot2(a0, b0, 0.f, false), false);
#else
  half2T p = a0*b0 + a1*b1;
  return (float)p.x + (float)p.y;
#endif
}
static __device__ __forceinline__ half2T pk2(float e){
#if __has_builtin(__builtin_amdgcn_cvt_pkrtz)
  union { __fp16 __attribute__((ext_vector_type(2))) p; half2T h; } c;
  c.p = __builtin_amdgcn_cvt_pkrtz(e, e);
  return c.h;
#else
  half2T r; r.x = (halfT)e; r.y = (halfT)e; return r;
#endif
}

__global__ void k_wt(const float* __restrict__ wlh, const float* __restrict__ wm,
                     halfT* __restrict__ wH){
  int i = blockIdx.x * 256 + threadIdx.x;
  if (i < 12288)      wH[i] = (halfT)wlh[i];
  else if (i < 61440) wH[i] = (halfT)wm[i - 12288];
}

#define OT_CS 276
#define OT_RS 68
#define QK_H  12288   // high region offset, u16 (qk capacity 24576 u16)
// exp2-folded scales: scale * log2(e)
#define SC_LH 0.36067376022224085f
#define SC_M  0.25506120808935443f

// low/high conv: K=64, T=192; 12 M-tiles split by ms; linear qk writes
static __device__ __forceinline__ void conv64(const halfT* __restrict__ w,
    const uint16_t* __restrict__ bands, uint16_t* __restrict__ qk,
    int band, int mrow, int g, int ms, int pxb, int qoff){
  half8 bfr[2];
  #pragma unroll
  for (int ks = 0; ks < 2; ++ks){
    H8 t; int cb = ks*32 + g*8;
    #pragma unroll
    for (int k = 0; k < 8; ++k)
      t.s[k] = bands[band*4096 + (cb + k)*64 + (pxb ^ (g << 4))];
    bfr[ks] = t.v;
  }
  #pragma unroll
  for (int mi = 0; mi < 6; ++mi){
    int mt = ms*6 + mi;
    f32x4 acc = {0.f,0.f,0.f,0.f};
    #pragma unroll
    for (int ks = 0; ks < 2; ++ks){
      half8 a = *(const half8*)&w[(mt*16 + mrow)*64 + ks*32 + g*8];
      acc = __builtin_amdgcn_mfma_f32_16x16x32_f16(a, bfr[ks], acc, 0, 0, 0);
    }
    uint16_t* wp = qk + qoff + mt*1024;
    wp[0]   = f2h(acc[0]);
    wp[4]   = f2h(acc[1]);
    wp[128] = f2h(acc[2]);
    wp[132] = f2h(acc[3]);
  }
}

// low/high attention, packed-f16 PV -> park 4 u32 into yslab
static __device__ __forceinline__ void attn16p(const uint16_t* __restrict__ qs,
    int m, int np, int W, uint32_t* __restrict__ yslab, int tid){
  const halfT sh = (halfT)SC_LH;
  const half8 s8 = {sh,sh,sh,sh,sh,sh,sh,sh};
  const uint16_t* qb_ = qs + (m >> 1)*256 + np*128 + W*8;
  const uint16_t* kb_ = qs + 4096 + np*128 + W*8;
  const uint16_t* vb_ = qs + 8192 + np*128 + W*8;
  H8 qg; qg.v = (*(const half8*)qb_) * s8;
  float sum0 = 0.f, sum1 = 0.f;
  half2T A0 = {(halfT)0,(halfT)0}, A1 = A0, B0 = A0, B1 = A0;
  #pragma unroll
  for (int d = 0; d < 16; ++d){
    H8 kg, vg;
    kg.v = *(const half8*)&kb_[d*256];
    vg.v = *(const half8*)&vb_[d*256];
    float a0 = dot4(qg.h2[0], qg.h2[1], kg.h2[0], kg.h2[1]);
    float a1 = dot4(qg.h2[2], qg.h2[3], kg.h2[2], kg.h2[3]);
    float e0 = exp2f(a0), e1 = exp2f(a1);
    sum0 += e0; sum1 += e1;
    half2T p0 = pk2(e0), p1 = pk2(e1);
    A0 += p0*vg.h2[0]; A1 += p0*vg.h2[1];
    B0 += p1*vg.h2[2]; B1 += p1*vg.h2[3];
  }
  halfT i0 = (halfT)__builtin_amdgcn_rcpf(sum0);
  halfT i1 = (halfT)__builtin_amdgcn_rcpf(sum1);
  half2T v0 = {i0,i0}, v1 = {i1,i1};
  H2U u0, u1, u2, u3;
  u0.h = A0*v0; u1.h = A1*v0; u2.h = B0*v1; u3.h = B1*v1;
  yslab[0*512 + tid] = u0.u;
  yslab[1*512 + tid] = u1.u;
  yslab[2*512 + tid] = u2.u;
  yslab[3*512 + tid] = u3.u;
}

#define IDWT(CH, Y0, Y1, Y2, Y3) { \
  float* otc = ot + (CH)*OT_CS + gw*4; \
  _Pragma("unroll") \
  for (int rp = 0; rp < 2; ++rp){ \
    float4 top, bot; \
    _Pragma("unroll") \
    for (int cp = 0; cp < 2; ++cp){ \
      int s2 = rp*2 + cp; \
      float ll = Y0[s2], lh = Y1[s2], hl = Y2[s2], hh = Y3[s2]; \
      float va = 0.5f*(ll - lh - hl + hh); \
      float vb = 0.5f*(ll - lh + hl - hh); \
      float vc = 0.5f*(ll + lh - hl - hh); \
      float vd = 0.5f*(ll + lh + hl + hh); \
      if (cp == 0){ top.x = va; top.y = vb; bot.x = vc; bot.y = vd; } \
      else        { top.z = va; top.w = vb; bot.z = vc; bot.w = vd; } \
    } \
    *(float4*)&otc[(2*rp)*OT_RS]   = top; \
    *(float4*)&otc[(2*rp+1)*OT_RS] = bot; \
  } }

__global__ __launch_bounds__(512, 4) void k_fused(const float* __restrict__ x,
    const halfT* __restrict__ wH, float* __restrict__ out){
  __shared__ __align__(16) uint8_t smem[81920];
  uint16_t* bands = (uint16_t*)smem;                 // 32768 B
  uint16_t* qk    = (uint16_t*)(smem + 32768);       // 49152 B (24576 u16)
  uint32_t* ybuf  = (uint32_t*)smem;                 // y slabs (dead bands)
  float*    ot    = (float*)smem;                    // reused at end

  const int tid = threadIdx.x;
  const int wv = tid >> 6, lane = tid & 63;
  const int unit = blockIdx.x >> 2, q4 = blockIdx.x & 3;
  const int b = unit >> 6, hw = unit & 63;
  const int col0 = q4 * 64;
  const float* xb = x + (size_t)b * 64 * 65536;
  const halfT* wM = wH + 12288;

  // ---------------- phase A: load x + Haar DWT -> bands -------------------
  #pragma unroll
  for (int it = 0; it < 4; ++it){
    int idx = it*512 + tid;
    int j = idx & 15, rp = (idx >> 4) & 1, c = idx >> 5;
    const float* src = xb + (size_t)c*65536 + (size_t)(4*hw + 2*rp)*256 + col0 + 4*j;
    float4 r0 = *(const float4*)src;
    float4 r1 = *(const float4*)(src + 256);
    float v0[4], v1[4];
    v0[0] = 0.5f*( r0.x + r0.y + r1.x + r1.y);
    v0[1] = 0.5f*(-r0.x - r0.y + r1.x + r1.y);
    v0[2] = 0.5f*(-r0.x + r0.y - r1.x + r1.y);
    v0[3] = 0.5f*( r0.x - r0.y - r1.x + r1.y);
    v1[0] = 0.5f*( r0.z + r0.w + r1.z + r1.w);
    v1[1] = 0.5f*(-r0.z - r0.w + r1.z + r1.w);
    v1[2] = 0.5f*(-r0.z + r0.w - r1.z + r1.w);
    v1[3] = 0.5f*( r0.z - r0.w - r1.z + r1.w);
    int base = c*64 + ((rp*32 + 2*j) ^ (((c >> 3) & 3) << 4));
    #pragma unroll
    for (int bb = 0; bb < 4; ++bb)
      *(uint32_t*)&bands[bb*4096 + base] =
          (uint32_t)f2h(v0[bb]) | ((uint32_t)f2h(v1[bb]) << 16);
  }
  __syncthreads();                                   // ---- barrier 1

  const int mrow = lane & 15, g = lane >> 4;
  const int m = lane & 31;
  const int W = wv*2 + (lane >> 5);   // window 0..15, fixed per thread
  const int A = 2*m;                  // output ch pair base
  const int np = m & 1;
  const int pxb = (wv & 3)*16 + mrow; // conv N-column
  const int ms = wv >> 2;
  const int wl = (pxb & 31) >> 1, qq = (pxb >> 5)*2 + (pxb & 1);
  const int qoff = g*256 + wl*8 + qq; // conv write base (linear layout)

  // ---- phase B: convL + convH (disjoint qk halves, 2x ILP) ---------------
  conv64(wH, bands, qk,        0, mrow, g, ms, pxb, qoff);   // low
  conv64(wH, bands, qk + QK_H, 3, mrow, g, ms, pxb, qoff);   // high
  __syncthreads();                                   // ---- barrier 2

  // ---- phase C: attnL + attnH (park y0, y3 in dead bands[0],[3]) ---------
  attn16p(qk,        m, np, W, ybuf + 0*2048, tid);
  attn16p(qk + QK_H, m, np, W, ybuf + 3*2048, tid);
  __syncthreads();                                   // ---- barrier 3

  // ---- phase D: convM (full qk): K=128 (bands 1,2), T=384 ----------------
  {
    half8 bfr[4];
    #pragma unroll
    for (int ks = 0; ks < 4; ++ks){
      H8 t; int band = 1 + (ks >> 1); int cb = (ks & 1)*32 + g*8;
      #pragma unroll
      for (int k = 0; k < 8; ++k)
        t.s[k] = bands[band*4096 + (cb + k)*64 + (pxb ^ (g << 4))];
      bfr[ks] = t.v;
    }
    #pragma unroll
    for (int mi = 0; mi < 12; ++mi){
      int mt = ms*12 + mi;
      f32x4 acc = {0.f,0.f,0.f,0.f};
      #pragma unroll
      for (int ks = 0; ks < 4; ++ks){
        half8 a = *(const half8*)&wM[(mt*16 + mrow)*128 + ks*32 + g*8];
        acc = __builtin_amdgcn_mfma_f32_16x16x32_f16(a, bfr[ks], acc, 0, 0, 0);
      }
      uint16_t* wp = qk + qoff + mt*1024;
      wp[0]   = f2h(acc[0]);
      wp[4]   = f2h(acc[1]);
      wp[128] = f2h(acc[2]);
      wp[132] = f2h(acc[3]);
    }
  }
  __syncthreads();                                   // ---- barrier 4

  // ---- phase E: attnM (park y1, y2 in dead bands[1],[2]) -----------------
  {
    const halfT shm = (halfT)SC_M;
    const half8 s8m = {shm,shm,shm,shm,shm,shm,shm,shm};
    const uint16_t* qa_ = qk + (m >> 1)*256 + np*128 + W*8;
    const uint16_t* kb_ = qk + 8192  + np*128 + W*8;   // G=32
    const uint16_t* vb_ = qk + 16384 + np*128 + W*8;   // G=64
    H8 qa, qb;
    qa.v = (*(const half8*)qa_) * s8m;                 // lh rows
    qb.v = (*(const half8*)&qa_[4096]) * s8m;          // hl rows (G+16)
    float sm0 = 0.f, sm1 = 0.f, sm2 = 0.f, sm3 = 0.f;
    half2T P0a = {(halfT)0,(halfT)0}, P0b = P0a, P1a = P0a, P1b = P0a;
    half2T P2a = P0a, P2b = P0a, P3a = P0a, P3b = P0a;
    #pragma unroll
    for (int dl = 0; dl < 32; ++dl){
      H8 kg, vg;
      kg.v = *(const half8*)&kb_[dl*256];
      vg.v = *(const half8*)&vb_[dl*256];
      float a0 = dot4(qa.h2[0], qa.h2[1], kg.h2[0], kg.h2[1]);
      float a1 = dot4(qa.h2[2], qa.h2[3], kg.h2[2], kg.h2[3]);
      float a2 = dot4(qb.h2[0], qb.h2[1], kg.h2[0], kg.h2[1]);
      float a3 = dot4(qb.h2[2], qb.h2[3], kg.h2[2], kg.h2[3]);
      float e0 = exp2f(a0), e1 = exp2f(a1);
      float e2 = exp2f(a2), e3 = exp2f(a3);
      sm0 += e0; sm1 += e1; sm2 += e2; sm3 += e3;
      half2T p0 = pk2(e0), p1 = pk2(e1), p2 = pk2(e2), p3 = pk2(e3);
      P0a += p0*vg.h2[0]; P0b += p0*vg.h2[1];
      P1a += p1*vg.h2[2]; P1b += p1*vg.h2[3];
      P2a += p2*vg.h2[0]; P2b += p2*vg.h2[1];
      P3a += p3*vg.h2[2]; P3b += p3*vg.h2[3];
    }
    halfT i0 = (halfT)__builtin_amdgcn_rcpf(sm0);
    halfT i1 = (halfT)__builtin_amdgcn_rcpf(sm1);
    halfT i2 = (halfT)__builtin_amdgcn_rcpf(sm2);
    halfT i3 = (halfT)__builtin_amdgcn_rcpf(sm3);
    half2T v0 = {i0,i0}, v1 = {i1,i1}, v2 = {i2,i2}, v3 = {i3,i3};
    uint32_t* y1s = ybuf + 1*2048;          // dead bands[1]
    uint32_t* y2s = ybuf + 2*2048;          // dead bands[2]
    H2U a0u, a1u, b0u, b1u, c0u, c1u, d0u, d1u;
    a0u.h = P0a*v0; a1u.h = P0b*v0; b0u.h = P1a*v1; b1u.h = P1b*v1;
    c0u.h = P2a*v2; c1u.h = P2b*v2; d0u.h = P3a*v3; d1u.h = P3b*v3;
    y1s[0*512 + tid] = a0u.u;
    y1s[1*512 + tid] = a1u.u;
    y1s[2*512 + tid] = b0u.u;
    y1s[3*512 + tid] = b1u.u;
    y2s[0*512 + tid] = c0u.u;
    y2s[1*512 + tid] = c1u.u;
    y2s[2*512 + tid] = d0u.u;
    y2s[3*512 + tid] = d1u.u;
  }

  // ---- read own y0-y3 (written by this thread; no barrier needed) ----
  float ya[4][2][4];
  #pragma unroll
  for (int p = 0; p < 4; ++p){
    #pragma unroll
    for (int w = 0; w < 4; ++w){
      uint32_t u = ybuf[p*2048 + w*512 + tid];
      ya[p][w >> 1][(w & 1)*2 + 0] = h2f((uint16_t)(u & 0xffffu));
      ya[p][w >> 1][(w & 1)*2 + 1] = h2f((uint16_t)(u >> 16));
    }
  }
  __syncthreads();                                   // ---- barrier 5

  // ---- iDWT in registers -> ot staging ----
  {
    const int gw = W ^ (m & 15);
    IDWT(A,     ya[0][0], ya[1][0], ya[2][0], ya[3][0]);
    IDWT(A + 1, ya[0][1], ya[1][1], ya[2][1], ya[3][1]);
  }
  __syncthreads();                                   // ---- barrier 6

  // ---- coalesced store (full-line writes) ----
  #pragma unroll
  for (int it = 0; it < 2; ++it){
    int s = it*512 + tid;
    int ch = s >> 4, row = (s >> 2) & 3, seg = s & 3;
    int sw = (ch >> 1) & 15;
    const float* rowp = &ot[ch*OT_CS + row*OT_RS];
    float4 v0 = *(const float4*)&rowp[((seg*4+0) ^ sw)*4];
    float4 v1 = *(const float4*)&rowp[((seg*4+1) ^ sw)*4];
    float4 v2 = *(const float4*)&rowp[((seg*4+2) ^ sw)*4];
    float4 v3 = *(const float4*)&rowp[((seg*4+3) ^ sw)*4];
    float* dst = out + (((size_t)b*64 + ch)*256 + (size_t)(4*hw + row))*256 + col0 + seg*16;
    ((float4*)dst)[0] = v0; ((float4*)dst)[1] = v1;
    ((float4*)dst)[2] = v2; ((float4*)dst)[3] = v3;
  }
}

// ---------------------------------------------------------------------------
extern "C" void kernel_launch(void* const* d_in, const int* in_sizes, int n_in,
                              void* d_out, int out_size, void* d_ws, size_t ws_size,
                              hipStream_t stream){
  const float* x   = (const float*)d_in[0];
  const float* wlh = (const float*)d_in[1];
  const float* wm  = (const float*)d_in[2];
  float* out = (float*)d_out;
  halfT* wH = (halfT*)d_ws;                // 61440 f16 = 122880 B

  hipLaunchKernelGGL(k_wt,    dim3(240),  dim3(256), 0, stream, wlh, wm, wH);
  hipLaunchKernelGGL(k_fused, dim3(2048), dim3(512), 0, stream, x, wH, out);
}